// Round 5
// baseline (192.068 us; speedup 1.0000x reference)
//
#include <hip/hip_runtime.h>
#include <hip/hip_bf16.h>
#include <stdint.h>

typedef short s16x8 __attribute__((ext_vector_type(8)));
typedef float f32x4 __attribute__((ext_vector_type(4)));

static constexpr int DDIM = 256;
static constexpr float TEN_LOG2E = 14.4269504088896340736f; // 10 * log2(e)
static constexpr unsigned NBLK = 512;

using u32_glb = __attribute__((address_space(1))) unsigned int;
using u32_lds = __attribute__((address_space(3))) unsigned int;

// ================= Fused persistent kernel: normalize -> Gram/exp -> finalize ========
// 512 blocks x 256 threads, all co-resident (51 KB LDS -> >=2 blocks/CU capacity = 512+).
// Grid-wide sync via device-scope atomic counter + __threadfence (G16 pattern); sync
// counters zeroed by a 16-byte hipMemsetAsync before launch (graph-capturable).
//
// Phase A (normalize+pack): block g normalizes rows [16g,16g+16) and packs them into
//   MFMA-fragment order: packed[((g*8+kt)*64+lane)*8..] = bf16 P[16g+(lane&15)][kt*32+(lane>>4)*8..]
//   Each (group,kt) fragment = contiguous 1KB in exact lane order (so global_load_lds'
//   wave-uniform-base+lane*16 write lands it linearly). Blocks 0..7 zero row_s; block 0 zeros out.
// Phase B (Gram tiles): round-2-verbatim ring-3 pipeline (the best measured: 51.5us),
//   block b handles tiles {b, b+512, ...} of the 2080 upper-triangle 128x128 tiles.
//   Per tile: prologue stages slots 0,1 -> vmcnt(4) -> barrier; 8 kt steps with
//   stage(kt+2), counted vmcnt(4) (never 0 until the tile's last loads), 16 MFMA/kt/wave.
//   Epilogue: exp2, diag mask, positive pairs, disjoint per-wave LDS partials,
//   one global atomic per row/col.
// Phase C (finalize): blocks 0..7 compute sum(log(row_s)-pos)/8192 into out.
__global__ __launch_bounds__(256) void fused_kernel(
    const float* __restrict__ zi, const float* __restrict__ zj,
    ushort* __restrict__ packed, float* __restrict__ row_s,
    float* __restrict__ pos_out, float* __restrict__ out,
    unsigned* __restrict__ sync0, unsigned* __restrict__ sync1)
{
    __shared__ ushort sbuf[3][16][512];   // 48 KB ring (phase B); phase A scratch aliases it
    __shared__ float rsum_lds[4][64];     // per-wave row partials (disjoint, no atomics)
    __shared__ float csum_lds[4][64];     // per-wave col partials

    const int tid  = threadIdx.x;
    const int w    = tid >> 6;
    const int lane = tid & 63;
    const int q    = lane >> 4;
    const int l15  = lane & 15;

    // ---------------- Phase A: normalize + pack (block = group blockIdx.x) ----------
    {
        ushort* plds = (ushort*)sbuf;     // 8 KB scratch, aliases ring (phase-separated)
        if (blockIdx.x < 8) {
            ((float4*)row_s)[blockIdx.x * 256 + tid] = (float4){0.f, 0.f, 0.f, 0.f};
            if (blockIdx.x == 0 && tid == 0) out[0] = 0.0f;
        }
        const int r = tid >> 4;           // row within group
        const int c = tid & 15;           // 16 threads per row
        const int row = blockIdx.x * 16 + r;
        const float* src = (row < 4096) ? (zi + (size_t)row * DDIM)
                                        : (zj + (size_t)(row - 4096) * DDIM);
        float4 v[4];
        #pragma unroll
        for (int j = 0; j < 4; ++j) v[j] = ((const float4*)src)[c + j * 16];

        float ss = 0.0f;
        #pragma unroll
        for (int j = 0; j < 4; ++j)
            ss += v[j].x * v[j].x + v[j].y * v[j].y + v[j].z * v[j].z + v[j].w * v[j].w;
        ss += __shfl_xor(ss, 1, 64);
        ss += __shfl_xor(ss, 2, 64);
        ss += __shfl_xor(ss, 4, 64);
        ss += __shfl_xor(ss, 8, 64);
        const float inv = 1.0f / fmaxf(sqrtf(ss), 1e-8f);

        #pragma unroll
        for (int j = 0; j < 4; ++j) {
            ushort4 o;
            o.x = __builtin_bit_cast(unsigned short, __float2bfloat16(v[j].x * inv));
            o.y = __builtin_bit_cast(unsigned short, __float2bfloat16(v[j].y * inv));
            o.z = __builtin_bit_cast(unsigned short, __float2bfloat16(v[j].z * inv));
            o.w = __builtin_bit_cast(unsigned short, __float2bfloat16(v[j].w * inv));
            *(ushort4*)(plds + r * 256 + (c + j * 16) * 4) = o;
        }
        __syncthreads();

        #pragma unroll
        for (int h = 0; h < 2; ++h) {
            const int idx  = h * 256 + tid;
            const int kt   = idx >> 6;
            const int ln   = idx & 63;
            const int qq   = ln >> 4;
            const int ll   = ln & 15;
            s16x8 frag = *(const s16x8*)(plds + ll * 256 + kt * 32 + qq * 8);
            ((s16x8*)packed)[(size_t)(blockIdx.x * 8 + kt) * 64 + ln] = frag;
        }
    }

    // ---------------- Grid sync 1 (packed + row_s zeros visible device-wide) --------
    __syncthreads();                       // drains this block's vmem (stores retired to L2)
    if (tid == 0) {
        __threadfence();                   // release: L2 writeback
        atomicAdd(sync0, 1u);
        while (atomicAdd(sync0, 0u) < NBLK) __builtin_amdgcn_s_sleep(2);
        __threadfence();                   // acquire: L2 invalidate
    }
    __syncthreads();

    // ---------------- Phase B: Gram tiles (round-2 ring-3 pipeline) ------------------
    const int wm  = (w >> 1) * 64;
    const int wn  = (w & 1) * 64;
    const int fa0 = (w >> 1) * 4;
    const int fb0 = 8 + (w & 1) * 4;

    f32x4 acc[4][4];
    #pragma unroll
    for (int mi = 0; mi < 4; ++mi)
        #pragma unroll
        for (int ni = 0; ni < 4; ++ni)
            acc[mi][ni] = (f32x4){0.f, 0.f, 0.f, 0.f};

    for (int tile = blockIdx.x; tile < 2080; tile += (int)NBLK) {
        // ---- upper-triangle decode: tile -> (ti, tj), ti <= tj ----
        int ti = (int)(64.5f - sqrtf(64.5f * 64.5f - 2.0f * (float)tile));
        while ((ti + 1) * 64 - ((ti + 1) * ti) / 2 <= tile) ++ti;
        while (ti * 64 - (ti * (ti - 1)) / 2 > tile) --ti;
        const int tj = ti + (tile - (ti * 64 - (ti * (ti - 1)) / 2));
        const int r0 = ti * 128, c0 = tj * 128;
        const bool diag  = (ti == tj);
        const bool ptile = (tj == ti + 32);

        // per-wave staging sources: wave w stages fragments f = 4w..4w+3
        const ushort* sbase[4];
        #pragma unroll
        for (int si = 0; si < 4; ++si) {
            const int f = w * 4 + si;
            const int g = (f < 8) ? (ti * 8 + f) : (tj * 8 + (f - 8));
            sbase[si] = packed + (size_t)g * 4096 + (size_t)lane * 8;
        }

        auto stagek = [&](int slot, int kk) {
            #pragma unroll
            for (int si = 0; si < 4; ++si) {
                const int f = w * 4 + si;
                __builtin_amdgcn_global_load_lds(
                    (const u32_glb*)(sbase[si] + kk * 512),
                    (u32_lds*)&sbuf[slot][f][0], 16, 0, 0);
            }
        };

        // prologue: fill ring slots 0,1; wait for slot 0's 4 loads only (epilogue
        // stores/atomics from the previous tile are older -> retired by this wait too)
        stagek(0, 0);
        stagek(1, 1);
        asm volatile("s_waitcnt vmcnt(4)" ::: "memory");
        __builtin_amdgcn_s_barrier();

        #pragma unroll
        for (int kt = 0; kt < 8; ++kt) {
            if (kt < 6) stagek((kt + 2) % 3, kt + 2);   // 2-ahead prefetch

            s16x8 af[4], bfr[4];
            #pragma unroll
            for (int mi = 0; mi < 4; ++mi)
                af[mi] = *(const s16x8*)&sbuf[kt % 3][fa0 + mi][lane * 8];
            #pragma unroll
            for (int ni = 0; ni < 4; ++ni)
                bfr[ni] = *(const s16x8*)&sbuf[kt % 3][fb0 + ni][lane * 8];

            #pragma unroll
            for (int mi = 0; mi < 4; ++mi)
                #pragma unroll
                for (int ni = 0; ni < 4; ++ni)
                    acc[mi][ni] = __builtin_amdgcn_mfma_f32_16x16x32_bf16(
                        af[mi], bfr[ni], acc[mi][ni], 0, 0, 0);

            // counted wait: group kt+1 (oldest outstanding) retired; group kt+2 in flight
            if (kt < 6)       asm volatile("s_waitcnt vmcnt(4)" ::: "memory");
            else if (kt == 6) asm volatile("s_waitcnt vmcnt(0)" ::: "memory");
            if (kt < 7) __builtin_amdgcn_s_barrier();
            // slot-1 reads at kt=7 are protected from the NEXT tile's prologue stage
            // by the epilogue __syncthreads below.
        }

        // ---- epilogue: exp, diag mask, positives, disjoint row/col partials ----
        // C/D layout (16x16): col = lane&15, row = q*4 + r
        float rsum[4][4];
        float csum[4] = {0.f, 0.f, 0.f, 0.f};
        #pragma unroll
        for (int mi = 0; mi < 4; ++mi)
            #pragma unroll
            for (int r = 0; r < 4; ++r) rsum[mi][r] = 0.0f;

        #pragma unroll
        for (int mi = 0; mi < 4; ++mi)
            #pragma unroll
            for (int ni = 0; ni < 4; ++ni)
                #pragma unroll
                for (int r = 0; r < 4; ++r) {
                    const int lr = wm + mi * 16 + q * 4 + r;
                    const int lc = wn + ni * 16 + l15;
                    float e = exp2f(acc[mi][ni][r] * TEN_LOG2E);
                    if (diag && lr == lc) e = 0.0f;
                    rsum[mi][r] += e;
                    csum[ni]    += e;
                    if (ptile && lr == lc) {
                        const float v = acc[mi][ni][r] * 10.0f;
                        pos_out[r0 + lr] = v;
                        pos_out[c0 + lr] = v;
                    }
                    acc[mi][ni][r] = 0.0f;   // reset for next tile
                }

        #pragma unroll
        for (int mi = 0; mi < 4; ++mi)
            #pragma unroll
            for (int r = 0; r < 4; ++r) {
                float v = rsum[mi][r];
                v += __shfl_xor(v, 1, 64);
                v += __shfl_xor(v, 2, 64);
                v += __shfl_xor(v, 4, 64);
                v += __shfl_xor(v, 8, 64);
                if (l15 == 0) rsum_lds[w][mi * 16 + q * 4 + r] = v;
            }
        #pragma unroll
        for (int ni = 0; ni < 4; ++ni) {
            float v = csum[ni];
            v += __shfl_xor(v, 16, 64);
            v += __shfl_xor(v, 32, 64);
            if (lane < 16) csum_lds[w][ni * 16 + l15] = v;
        }

        __syncthreads();   // partials visible; also fences kt=7 slot reads vs next prologue

        if (tid < 128) {
            const float v = rsum_lds[(tid >> 6) * 2][tid & 63]
                          + rsum_lds[(tid >> 6) * 2 + 1][tid & 63];
            atomicAdd(&row_s[r0 + tid], v);
        } else if (!diag) {
            const int c = tid - 128;
            const float v = (c < 64) ? (csum_lds[0][c] + csum_lds[2][c])
                                     : (csum_lds[1][c - 64] + csum_lds[3][c - 64]);
            atomicAdd(&row_s[c0 + c], v);
        }
        __syncthreads();   // partial-LDS reads done before next tile's epilogue writes
    }

    // ---------------- Grid sync 2 (row_s atomics + pos stores complete) --------------
    __syncthreads();
    if (tid == 0) {
        __threadfence();
        atomicAdd(sync1, 1u);
        while (atomicAdd(sync1, 0u) < NBLK) __builtin_amdgcn_s_sleep(2);
        __threadfence();
    }
    __syncthreads();

    // ---------------- Phase C: finalize loss (blocks 0..7) ---------------------------
    if (blockIdx.x < 8) {
        const int i = blockIdx.x * 256 + tid;   // float4 index, 2048 total
        float4 s = ((const float4*)row_s)[i];
        float4 p = ((const float4*)pos_out)[i];
        float local = (__logf(s.x) - p.x) + (__logf(s.y) - p.y)
                    + (__logf(s.z) - p.z) + (__logf(s.w) - p.w);
        #pragma unroll
        for (int off = 32; off > 0; off >>= 1) local += __shfl_xor(local, off, 64);
        __shared__ float red[4];
        if ((tid & 63) == 0) red[tid >> 6] = local;
        __syncthreads();
        if (tid == 0)
            atomicAdd(out, (red[0] + red[1] + red[2] + red[3]) * (1.0f / 8192.0f));
    }
}

// ---------------- Launch ----------------
extern "C" void kernel_launch(void* const* d_in, const int* in_sizes, int n_in,
                              void* d_out, int out_size, void* d_ws, size_t ws_size,
                              hipStream_t stream)
{
    const float* zi = (const float*)d_in[0];
    const float* zj = (const float*)d_in[1];

    ushort* packed  = (ushort*)d_ws;                                    // 4 MB fragment-order bf16
    float* row_s    = (float*)((char*)d_ws + (4u << 20));               // 8192 fp32
    float* pos      = (float*)((char*)d_ws + (4u << 20) + (32u << 10)); // 8192 fp32
    unsigned* syncc = (unsigned*)((char*)d_ws + (4u << 20) + (64u << 10)); // 2 counters
    float* out      = (float*)d_out;

    hipMemsetAsync(syncc, 0, 16, stream);   // zero grid-sync counters (graph-capturable)
    hipLaunchKernelGGL(fused_kernel, dim3(NBLK), dim3(256), 0, stream,
                       zi, zj, packed, row_s, pos, out, syncc, syncc + 1);
}

// Round 7
// 106.664 us; speedup vs baseline: 1.8007x; 1.8007x over previous
//
#include <hip/hip_runtime.h>
#include <hip/hip_bf16.h>
#include <stdint.h>

typedef short s16x8 __attribute__((ext_vector_type(8)));
typedef float f32x4 __attribute__((ext_vector_type(4)));

static constexpr int DDIM = 256;
static constexpr float TEN_LOG2E = 14.4269504088896340736f; // 10 * log2(e)

using u32_glb = __attribute__((address_space(1))) unsigned int;
using u32_lds = __attribute__((address_space(3))) unsigned int;

// ---------------- Kernel 1: normalize + pack into MFMA-fragment order ----------------
// 512 blocks x 256 threads; block g handles rows [16g, 16g+16). Output layout:
// packed[((g*8 + kt)*64 + lane)*8 .. +8] = bf16 P[16g + (lane&15)][kt*32 + (lane>>4)*8 ..]
// Each (group, kt) fragment is one contiguous 1KB block in exact lane order.
// Also zero-inits row_s[8192] (blocks 0..7) and out[0] (block 0).
__global__ __launch_bounds__(256) void normalize_pack_kernel(
    const float* __restrict__ zi, const float* __restrict__ zj,
    ushort* __restrict__ packed, float* __restrict__ row_s, float* __restrict__ out)
{
    __shared__ ushort lds[16 * 256];

    if (blockIdx.x < 8) {
        ((float4*)row_s)[blockIdx.x * 256 + threadIdx.x] = (float4){0.f, 0.f, 0.f, 0.f};
        if (blockIdx.x == 0 && threadIdx.x == 0) out[0] = 0.0f;
    }

    const int t = threadIdx.x;
    const int r = t >> 4;            // 0..15: row within group
    const int c = t & 15;            // 16 threads per row
    const int row = blockIdx.x * 16 + r;
    const float* src = (row < 4096) ? (zi + (size_t)row * DDIM)
                                    : (zj + (size_t)(row - 4096) * DDIM);
    float4 v[4];
    #pragma unroll
    for (int j = 0; j < 4; ++j) v[j] = ((const float4*)src)[c + j * 16];

    float ss = 0.0f;
    #pragma unroll
    for (int j = 0; j < 4; ++j)
        ss += v[j].x * v[j].x + v[j].y * v[j].y + v[j].z * v[j].z + v[j].w * v[j].w;
    ss += __shfl_xor(ss, 1, 64);
    ss += __shfl_xor(ss, 2, 64);
    ss += __shfl_xor(ss, 4, 64);
    ss += __shfl_xor(ss, 8, 64);
    const float inv = 1.0f / fmaxf(sqrtf(ss), 1e-8f);

    #pragma unroll
    for (int j = 0; j < 4; ++j) {
        ushort4 o;
        o.x = __builtin_bit_cast(unsigned short, __float2bfloat16(v[j].x * inv));
        o.y = __builtin_bit_cast(unsigned short, __float2bfloat16(v[j].y * inv));
        o.z = __builtin_bit_cast(unsigned short, __float2bfloat16(v[j].z * inv));
        o.w = __builtin_bit_cast(unsigned short, __float2bfloat16(v[j].w * inv));
        *(ushort4*)(lds + r * 256 + (c + j * 16) * 4) = o;
    }
    __syncthreads();

    #pragma unroll
    for (int h = 0; h < 2; ++h) {
        const int idx  = h * 256 + t;
        const int kt   = idx >> 6;
        const int lane = idx & 63;
        const int q    = lane >> 4;
        const int l15  = lane & 15;
        s16x8 frag = *(const s16x8*)(lds + l15 * 256 + kt * 32 + q * 8);
        ((s16x8*)packed)[(size_t)(blockIdx.x * 8 + kt) * 64 + lane] = frag;
    }
}

// ---------------- Kernel 2: 256x256 Gram tiles, 8 waves, double-buffered LDS ---------
// 528 blocks = 32*33/2 upper-triangle tiles of 256x256. 8 waves (512 thr), wave grid
// 4x2: wave w=(wr*2+wc) owns rows [wr*64,+64) x cols [wc*128,+128) -> acc[4][8].
// Per kt (K=32 slice): 32 fragments (16 A + 16 B, 32 KB) staged cooperatively via
// global_load_lds (4/wave, linear dest); each wave ds_read_b128's 4 A + 8 B frags and
// issues 32 MFMAs. Density: 256 MFMAs per 32 KB staged = 2x the 128-tile version; per-
// block fixed costs (prologue, 8 barriers, epilogue) amortize over 4x the output.
// Double buffer + drain sync per kt (round-1 proven-correct pattern). Epilogue: exp2,
// diag mask, positives, disjoint per-wave LDS partials, one global atomic per row/col.
__global__ __launch_bounds__(512, 1) void gram256_kernel(
    const ushort* __restrict__ packed,
    float* __restrict__ row_s,
    float* __restrict__ pos_out)
{
    __shared__ ushort sbuf[2][32][512];   // 64 KB: frags 0..15 = A groups, 16..31 = B
    __shared__ float rsum_lds[8][64];     // per-wave row partials (wave rows)
    __shared__ float csum_lds[8][128];    // per-wave col partials (wave cols)

    const int tid  = threadIdx.x;
    const int w    = tid >> 6;           // 0..7
    const int lane = tid & 63;
    const int q    = lane >> 4;
    const int l15  = lane & 15;
    const int wr   = w >> 1;             // 0..3: 64-row band
    const int wc   = w & 1;              // 0..1: 128-col band

    // ---- upper-triangle decode over 32x32 tile grid: block b -> (ti, tj), ti<=tj ----
    const int b = blockIdx.x;
    int ti = (int)(32.5f - sqrtf(32.5f * 32.5f - 2.0f * (float)b));
    while ((ti + 1) * 32 - ((ti + 1) * ti) / 2 <= b) ++ti;
    while (ti * 32 - (ti * (ti - 1)) / 2 > b) --ti;
    const int tj = ti + (b - (ti * 32 - (ti * (ti - 1)) / 2));
    const int r0 = ti * 256, c0 = tj * 256;
    const bool diag  = (ti == tj);
    const bool ptile = (tj == ti + 16);   // contains positive-pair diagonal (offset 4096)

    // staging sources: wave w stages fragments f = 4w..4w+3 (32 total)
    // f<16 -> A group ti*16+f ; f>=16 -> B group tj*16+(f-16)
    const ushort* sbase[4];
    #pragma unroll
    for (int si = 0; si < 4; ++si) {
        const int f = w * 4 + si;
        const int g = (f < 16) ? (ti * 16 + f) : (tj * 16 + (f - 16));
        sbase[si] = packed + (size_t)g * 4096 + (size_t)lane * 8;   // kt=0 fragment
    }
    auto stagek = [&](int buf, int kt) {
        #pragma unroll
        for (int si = 0; si < 4; ++si) {
            const int f = w * 4 + si;
            __builtin_amdgcn_global_load_lds(
                (const u32_glb*)(sbase[si] + kt * 512),
                (u32_lds*)&sbuf[buf][f][0], 16, 0, 0);
        }
    };

    f32x4 acc[4][8];
    #pragma unroll
    for (int mi = 0; mi < 4; ++mi)
        #pragma unroll
        for (int ni = 0; ni < 8; ++ni)
            acc[mi][ni] = (f32x4){0.f, 0.f, 0.f, 0.f};

    stagek(0, 0);
    __syncthreads();   // buffer 0 ready (vmcnt drained by syncthreads semantics)

    for (int kt = 0; kt < 8; ++kt) {
        const int cur = kt & 1;
        if (kt < 7) stagek(cur ^ 1, kt + 1);   // next slice's loads fly under compute

        s16x8 af[4], bfr[8];
        #pragma unroll
        for (int mi = 0; mi < 4; ++mi)
            af[mi] = *(const s16x8*)&sbuf[cur][wr * 4 + mi][lane * 8];
        #pragma unroll
        for (int ni = 0; ni < 8; ++ni)
            bfr[ni] = *(const s16x8*)&sbuf[cur][16 + wc * 8 + ni][lane * 8];

        #pragma unroll
        for (int mi = 0; mi < 4; ++mi)
            #pragma unroll
            for (int ni = 0; ni < 8; ++ni)
                acc[mi][ni] = __builtin_amdgcn_mfma_f32_16x16x32_bf16(
                    af[mi], bfr[ni], acc[mi][ni], 0, 0, 0);

        __syncthreads();   // all reads of cur done + staged cur^1 landed
    }

    // ---- epilogue: exp, diag mask, positive extraction, row+col partial sums ----
    // C/D layout (16x16): col = lane&15, row = q*4 + r
    float rsum[4][4];
    float csum[8] = {0.f, 0.f, 0.f, 0.f, 0.f, 0.f, 0.f, 0.f};
    #pragma unroll
    for (int mi = 0; mi < 4; ++mi)
        #pragma unroll
        for (int r = 0; r < 4; ++r) rsum[mi][r] = 0.0f;

    #pragma unroll
    for (int mi = 0; mi < 4; ++mi)
        #pragma unroll
        for (int ni = 0; ni < 8; ++ni)
            #pragma unroll
            for (int r = 0; r < 4; ++r) {
                const int lr = wr * 64 + mi * 16 + q * 4 + r;    // local row in 256
                const int lc = wc * 128 + ni * 16 + l15;         // local col in 256
                float e = exp2f(acc[mi][ni][r] * TEN_LOG2E);
                if (diag && lr == lc) e = 0.0f;                  // mask self-similarity
                rsum[mi][r] += e;
                csum[ni]    += e;
                if (ptile && lr == lc) {                         // positive: col=row+4096
                    const float v = acc[mi][ni][r] * 10.0f;
                    pos_out[r0 + lr] = v;
                    pos_out[c0 + lr] = v;
                }
            }

    // row partials: reduce across 16 lanes (cols) per quad; lanes l15==0 store 64 rows
    #pragma unroll
    for (int mi = 0; mi < 4; ++mi)
        #pragma unroll
        for (int r = 0; r < 4; ++r) {
            float v = rsum[mi][r];
            v += __shfl_xor(v, 1, 64);
            v += __shfl_xor(v, 2, 64);
            v += __shfl_xor(v, 4, 64);
            v += __shfl_xor(v, 8, 64);
            if (l15 == 0) rsum_lds[w][mi * 16 + q * 4 + r] = v;
        }
    // col partials: reduce across 4 row-quads; lanes q==0 store 128 cols
    #pragma unroll
    for (int ni = 0; ni < 8; ++ni) {
        float v = csum[ni];
        v += __shfl_xor(v, 16, 64);
        v += __shfl_xor(v, 32, 64);
        if (lane < 16) csum_lds[w][ni * 16 + l15] = v;
    }

    __syncthreads();

    // combine wave partials; one global atomic per row (tid<256) / per col (tid>=256)
    if (tid < 256) {
        const int rr  = tid & 63;
        const int wr2 = tid >> 6;
        const float v = rsum_lds[wr2 * 2 + 0][rr] + rsum_lds[wr2 * 2 + 1][rr];
        atomicAdd(&row_s[r0 + tid], v);
    } else if (!diag) {
        const int c   = tid - 256;
        const int wcc = c >> 7;
        const int cc  = c & 127;
        const float v = csum_lds[0 * 2 + wcc][cc] + csum_lds[1 * 2 + wcc][cc]
                      + csum_lds[2 * 2 + wcc][cc] + csum_lds[3 * 2 + wcc][cc];
        atomicAdd(&row_s[c0 + c], v);
    }
}

// ---------------- Kernel 3: finalize loss ----------------
__global__ __launch_bounds__(256) void finalize_kernel(
    const float* __restrict__ row_s, const float* __restrict__ pos,
    float* __restrict__ out)
{
    const int i = blockIdx.x * 256 + threadIdx.x;   // float4 index, 2048 total
    float4 s = ((const float4*)row_s)[i];
    float4 p = ((const float4*)pos)[i];
    float local = (__logf(s.x) - p.x) + (__logf(s.y) - p.y)
                + (__logf(s.z) - p.z) + (__logf(s.w) - p.w);
    #pragma unroll
    for (int off = 32; off > 0; off >>= 1) local += __shfl_xor(local, off, 64);
    __shared__ float red[4];
    if ((threadIdx.x & 63) == 0) red[threadIdx.x >> 6] = local;
    __syncthreads();
    if (threadIdx.x == 0)
        atomicAdd(out, (red[0] + red[1] + red[2] + red[3]) * (1.0f / 8192.0f));
}

// ---------------- Launch ----------------
extern "C" void kernel_launch(void* const* d_in, const int* in_sizes, int n_in,
                              void* d_out, int out_size, void* d_ws, size_t ws_size,
                              hipStream_t stream)
{
    const float* zi = (const float*)d_in[0];
    const float* zj = (const float*)d_in[1];

    ushort* packed = (ushort*)d_ws;                                    // 4 MB fragment-order bf16
    float* row_s   = (float*)((char*)d_ws + (4u << 20));               // 8192 fp32
    float* pos     = (float*)((char*)d_ws + (4u << 20) + (32u << 10)); // 8192 fp32
    float* out     = (float*)d_out;

    hipLaunchKernelGGL(normalize_pack_kernel, dim3(512), dim3(256), 0, stream,
                       zi, zj, packed, row_s, out);
    hipLaunchKernelGGL(gram256_kernel, dim3(528), dim3(512), 0, stream,
                       packed, row_s, pos);
    hipLaunchKernelGGL(finalize_kernel, dim3(8), dim3(256), 0, stream, row_s, pos, out);
}